// Round 2
// baseline (308.551 us; speedup 1.0000x reference)
//
#include <hip/hip_runtime.h>
#include <stdint.h>

typedef unsigned long long u64;

#define Bn 4
#define CINn 32
#define Hn 64
#define Wn 64
#define Sn 4096
#define KCn 32
#define Mn 16
#define COUTn 32
#define AREAn 9
#define Fn 288
#define NITER 10
#define FXSCALE 4294967296.0
#define NBLK_B 32          // k_main blocks per batch
#define LDK 292            // padded LDS row stride (floats) in k_out

static __device__ __forceinline__ float relu_(float v){ return v > 0.f ? v : 0.f; }
static __device__ __forceinline__ float sigmoid_(float v){ return 1.f / (1.f + expf(-v)); }

// ---------------------------------------------------------------------------
// Per-batch software barrier (32 blocks). bar[0]=count, bar[16]=generation.
// Agent-scope acq/rel atomics make ordinary global accesses visible across it
// (same mechanism cooperative-groups grid.sync uses).
// ---------------------------------------------------------------------------
static __device__ __forceinline__ void batch_barrier(unsigned* bar){
    __syncthreads();
    if (threadIdx.x == 0){
        unsigned* cnt = bar;
        unsigned* gen = bar + 16;
        unsigned g = __hip_atomic_load(gen, __ATOMIC_RELAXED, __HIP_MEMORY_SCOPE_AGENT);
        unsigned a = __hip_atomic_fetch_add(cnt, 1u, __ATOMIC_ACQ_REL, __HIP_MEMORY_SCOPE_AGENT);
        if (a == (unsigned)(NBLK_B - 1)){
            __hip_atomic_store(cnt, 0u, __ATOMIC_RELAXED, __HIP_MEMORY_SCOPE_AGENT);
            __hip_atomic_fetch_add(gen, 1u, __ATOMIC_RELEASE, __HIP_MEMORY_SCOPE_AGENT);
        } else {
            while (__hip_atomic_load(gen, __ATOMIC_ACQUIRE, __HIP_MEMORY_SCOPE_AGENT) == g)
                __builtin_amdgcn_s_sleep(4);
        }
    }
    __syncthreads();
}

// ---------------------------------------------------------------------------
// K0: feat = 3x3 mean; zero fixed-point accumulators + barrier state.
// Grid exactly B*CIN*S threads.
// ---------------------------------------------------------------------------
__global__ __launch_bounds__(256) void k_init(const float* __restrict__ x,
                                              float* __restrict__ feat,
                                              u64* __restrict__ gsum,
                                              unsigned* __restrict__ gcnt,
                                              unsigned* __restrict__ bar){
    int g = blockIdx.x * 256 + threadIdx.x;
    if (g < 3 * Bn * KCn * CINn) gsum[g] = 0ull;
    if (g < 3 * Bn * KCn)        gcnt[g] = 0u;
    if (g < 4 * 32)              bar[g]  = 0u;
    int p = g & (Sn - 1);
    int c = (g >> 12) & (CINn - 1);
    int b = g >> 17;
    int y = p >> 6, xx = p & 63;
    const float* xc = x + ((size_t)(b * CINn + c) << 12);
    float s = 0.f;
    #pragma unroll
    for (int i = 0; i < 3; ++i){
        int yy = y + i - 1;
        if (yy < 0 || yy >= Hn) continue;
        #pragma unroll
        for (int j = 0; j < 3; ++j){
            int xj = xx + j - 1;
            if (xj < 0 || xj >= Wn) continue;
            s += xc[(yy << 6) + xj];
        }
    }
    feat[g] = s * (1.f / 9.f);
}

// ---------------------------------------------------------------------------
// K1: fused pipeline. Grid = 128 blocks (4 batches x 32), 256 threads.
// Phases: 11 KMeans iters (k-split x2, bucket-sorted fixed-point sums),
// counting sort (block 0/batch), then per-cluster {segmean, MLPs, heads}.
// ---------------------------------------------------------------------------
struct AssignSh {
    u64   fxL[128][32];     // per-pixel fixed-point features (persist across iters)
    float cent[KCn][CINn];
    float c2[KCn];
    float bestd[256];
    int   bestk[256];
    unsigned cnt32[KCn];
    unsigned base32[KCn + 1];
    unsigned scat[KCn];
    int   plist[128];
};
struct SortSh {
    unsigned hist[256][KCn];
    unsigned cnts[KCn];
    unsigned baseK[KCn + 1];
};
struct SmkSh {
    float centL[Fn];
    int   pl[256];
    float part1[16][16], part2[16][16];
    float hL[2][Mn];
    float kfL[2][Mn];
};
union ShU { AssignSh a; SortSh s; SmkSh m; };

__global__ __launch_bounds__(256) void k_main(const float* __restrict__ x,
        const float* __restrict__ feat,
        float* __restrict__ gcent, u64* __restrict__ gsum, unsigned* __restrict__ gcnt,
        int* __restrict__ idx, float* __restrict__ idxf,
        int* __restrict__ sorted, int* __restrict__ offs,
        const float* __restrict__ Wh1, const float* __restrict__ bh1,
        const float* __restrict__ Wh2, const float* __restrict__ bh2,
        const float* __restrict__ Wa,  const float* __restrict__ ba,
        const float* __restrict__ Wc,  const float* __restrict__ bc,
        const float* __restrict__ Wo,  const float* __restrict__ bo,
        const float* __restrict__ Wb1, const float* __restrict__ bb1,
        const float* __restrict__ Wb2, const float* __restrict__ bb2,
        const float* __restrict__ Wb3, const float* __restrict__ bb3,
        float* __restrict__ wcin, float* __restrict__ warea,
        float* __restrict__ wcout, float* __restrict__ biasb,
        unsigned* __restrict__ bars){
    __shared__ ShU sh;
    int tid  = threadIdx.x;
    int b    = blockIdx.x >> 5;
    int tnum = blockIdx.x & 31;
    unsigned* bar = bars + b * 32;

    // ---- pixel/thread mapping: 128 px per block, 2 threads per px (k-halves)
    int pxi  = tid & 127;
    int half = tid >> 7;
    int p    = tnum * 128 + pxi;

    float fv[CINn];
    #pragma unroll
    for (int c = 0; c < CINn; ++c) fv[c] = feat[(b * CINn + c) * Sn + p];
    float f2 = 0.f;
    #pragma unroll
    for (int c = 0; c < CINn; ++c) f2 = fmaf(fv[c], fv[c], f2);

    if (tid < 128){
        #pragma unroll
        for (int c = 0; c < CINn; ++c)
            sh.a.fxL[tid][c] = (u64)llrint((double)fv[c] * FXSCALE);
    }

    // ---------------- KMeans iterations ----------------
    for (int iter = 0; iter <= NITER; ++iter){
        int prev = (iter + 2) % 3;
        int cur  = iter % 3;
        int nxt  = (iter + 1) % 3;

        for (int e = tid; e < KCn * CINn; e += 256){
            int k = e >> 5, c = e & 31;
            float v;
            if (iter == 0){
                v = feat[(b * CINn + c) * Sn + k * (Sn / KCn)];
            } else {
                u64 sv     = gsum[((prev * Bn + b) * KCn + k) * CINn + c];
                unsigned cn = gcnt[(prev * Bn + b) * KCn + k];
                if (cn > 0) v = (float)((double)(long long)sv / ((double)cn * FXSCALE));
                else        v = gcent[(b * KCn + k) * CINn + c];
            }
            sh.a.cent[k][c] = v;
            if (tnum == 0){
                gcent[(b * KCn + k) * CINn + c] = v;
                gsum[((nxt * Bn + b) * KCn + k) * CINn + c] = 0ull;
            }
        }
        if (tnum == 0 && tid < KCn) gcnt[(nxt * Bn + b) * KCn + tid] = 0u;
        __syncthreads();
        if (tid < 32){
            float s = 0.f;
            #pragma unroll
            for (int c = 0; c < CINn; ++c) s = fmaf(sh.a.cent[tid][c], sh.a.cent[tid][c], s);
            sh.a.c2[tid] = s;
        } else if (tid < 64){
            sh.a.cnt32[tid - 32] = 0u;
        } else if (tid < 96){
            sh.a.scat[tid - 64] = 0u;
        }
        __syncthreads();

        // dot over this thread's k-half
        float best = 3.402823466e38f;
        int   bk   = half * 16;
        #pragma unroll 4
        for (int k = 0; k < 16; ++k){
            int kk = half * 16 + k;
            const float* cr = sh.a.cent[kk];
            float dot = 0.f;
            #pragma unroll
            for (int c = 0; c < CINn; ++c) dot = fmaf(fv[c], cr[c], dot);
            float d = f2 - 2.f * dot + sh.a.c2[kk];
            if (d < best){ best = d; bk = kk; }   // strict < = first-min
        }
        sh.a.bestd[tid] = best;
        sh.a.bestk[tid] = bk;
        __syncthreads();

        int bi = -1;
        if (tid < 128){
            float d0 = sh.a.bestd[tid], d1 = sh.a.bestd[tid + 128];
            int   k0 = sh.a.bestk[tid], k1 = sh.a.bestk[tid + 128];
            bi = (d1 < d0) ? k1 : k0;             // tie -> lower-k half
            if (iter == NITER){
                idx[b * Sn + p]  = bi;
                idxf[b * Sn + p] = (float)bi;
            } else {
                atomicAdd(&sh.a.cnt32[bi], 1u);
            }
        }

        if (iter < NITER){
            __syncthreads();
            if (tid == 0){
                unsigned acc = 0;
                #pragma unroll
                for (int k = 0; k < KCn; ++k){ sh.a.base32[k] = acc; acc += sh.a.cnt32[k]; }
                sh.a.base32[KCn] = acc;
            }
            __syncthreads();
            if (tid < 128){
                unsigned pos = sh.a.base32[bi] + atomicAdd(&sh.a.scat[bi], 1u);
                sh.a.plist[pos] = tid;
            }
            __syncthreads();
            // per-(k, 4-channel-group) deterministic integer partial sums
            {
                int k  = tid >> 3;
                int cg = (tid & 7) * 4;
                unsigned s0 = sh.a.base32[k];
                unsigned nk = sh.a.cnt32[k];
                u64 a0 = 0, a1 = 0, a2 = 0, a3 = 0;
                for (unsigned i = 0; i < nk; ++i){
                    int px = sh.a.plist[s0 + i];
                    a0 += sh.a.fxL[px][cg + 0];
                    a1 += sh.a.fxL[px][cg + 1];
                    a2 += sh.a.fxL[px][cg + 2];
                    a3 += sh.a.fxL[px][cg + 3];
                }
                u64* gs = &gsum[((cur * Bn + b) * KCn + k) * CINn + cg];
                if (a0) atomicAdd(gs + 0, a0);
                if (a1) atomicAdd(gs + 1, a1);
                if (a2) atomicAdd(gs + 2, a2);
                if (a3) atomicAdd(gs + 3, a3);
                if ((tid & 7) == 0 && nk) atomicAdd(&gcnt[(cur * Bn + b) * KCn + k], nk);
            }
        }
        batch_barrier(bar);
    }

    // ---------------- counting sort (block 0 of each batch) ----------------
    if (tnum == 0){
        #pragma unroll
        for (int k = 0; k < KCn; ++k) sh.s.hist[tid][k] = 0u;
        int p0 = tid * 16;
        int myk[16];
        #pragma unroll
        for (int i = 0; i < 16; ++i){
            int k = idx[b * Sn + p0 + i];
            myk[i] = k;
            sh.s.hist[tid][k]++;
        }
        __syncthreads();
        if (tid < KCn){
            unsigned run = 0;
            for (int t2 = 0; t2 < 256; ++t2){ unsigned v = sh.s.hist[t2][tid]; sh.s.hist[t2][tid] = run; run += v; }
            sh.s.cnts[tid] = run;
        }
        __syncthreads();
        if (tid == 0){
            unsigned acc = 0;
            for (int k = 0; k < KCn; ++k){ sh.s.baseK[k] = acc; acc += sh.s.cnts[k]; }
            sh.s.baseK[KCn] = acc;
        }
        __syncthreads();
        if (tid <= KCn) offs[b * (KCn + 1) + tid] = (int)sh.s.baseK[tid];
        #pragma unroll
        for (int i = 0; i < 16; ++i){
            int k = myk[i];
            unsigned pos = sh.s.baseK[k] + sh.s.hist[tid][k];
            sh.s.hist[tid][k]++;
            sorted[b * Sn + pos] = p0 + i;
        }
    }
    batch_barrier(bar);

    // ---------------- segmean + MLPs + heads: one cluster per block ----------------
    int kk = tnum;
    int off0 = offs[b * (KCn + 1) + kk];
    int n    = offs[b * (KCn + 1) + kk + 1] - off0;

    // segmean (deterministic: ascending pixel order, fixed per-thread feature)
    {
        int fA = tid;           int cA = fA / 9, aA = fA - cA * 9;
        int dyA = aA / 3 - 1,   dxA = aA % 3 - 1;
        int fB = 256 + tid;     int cB = fB / 9, aB = fB - cB * 9;
        int dyB = aB / 3 - 1,   dxB = aB % 3 - 1;
        float sumA = 0.f, sumB = 0.f;
        for (int base = 0; base < n; base += 256){
            int m = min(256, n - base);
            __syncthreads();
            if (tid < m) sh.m.pl[tid] = sorted[b * Sn + off0 + base + tid];
            __syncthreads();
            for (int i = 0; i < m; ++i){
                int pp = sh.m.pl[i];
                int py = pp >> 6, px2 = pp & 63;
                int y1 = py + dyA, x1 = px2 + dxA;
                float v = (y1 >= 0 && y1 < Hn && x1 >= 0 && x1 < Wn)
                          ? x[((size_t)(b * CINn + cA) << 12) + (y1 << 6) + x1] : 0.f;
                sumA += v;
                if (tid < 32){
                    int y2 = py + dyB, x2 = px2 + dxB;
                    float v2 = (y2 >= 0 && y2 < Hn && x2 >= 0 && x2 < Wn)
                               ? x[((size_t)(b * CINn + cB) << 12) + (y2 << 6) + x2] : 0.f;
                    sumB += v2;
                }
            }
        }
        __syncthreads();
        float inv = 1.f / (float)max(n, 1);
        sh.m.centL[fA] = sumA * (float)max(n,1) * 0.f + sumA / (float)max(n, 1); // keep plain divide
        (void)inv;
        if (tid < 32) sh.m.centL[fB] = sumB / (float)max(n, 1);
    }
    __syncthreads();

    // layer-1 partials: rep covers 18 features
    {
        int j = tid & 15, rep = tid >> 4;
        float p1 = 0.f, p2 = 0.f;
        int fbeg = rep * 18;
        for (int ff = fbeg; ff < fbeg + 18; ++ff){
            float cv = sh.m.centL[ff];
            p1 = fmaf(cv, Wh1[ff * Mn + j], p1);
            p2 = fmaf(cv, Wb1[ff * Mn + j], p2);
        }
        sh.m.part1[rep][j] = p1;
        sh.m.part2[rep][j] = p2;
    }
    __syncthreads();
    if (tid < 32){
        int br = tid >> 4, j = tid & 15;
        float s = br ? bb1[j] : bh1[j];
        for (int r = 0; r < 16; ++r) s += br ? sh.m.part2[r][j] : sh.m.part1[r][j];
        sh.m.hL[br][j] = relu_(s);
    }
    __syncthreads();
    if (tid < 32){
        int br = tid >> 4, j = tid & 15;
        const float* W2 = br ? Wb2 : Wh2;
        float s = br ? bb2[j] : bh2[j];
        #pragma unroll
        for (int i = 0; i < Mn; ++i) s = fmaf(sh.m.hL[br][i], W2[i * Mn + j], s);
        sh.m.kfL[br][j] = relu_(s);
    }
    __syncthreads();
    if (tid < 32){
        int o = tid;
        float s1 = bc[o], s2 = bo[o], s3 = bb3[o];
        #pragma unroll
        for (int i = 0; i < Mn; ++i){
            float kv = sh.m.kfL[0][i];
            s1 = fmaf(kv, Wc[i * COUTn + o], s1);
            s2 = fmaf(kv, Wo[i * COUTn + o], s2);
            s3 = fmaf(sh.m.kfL[1][i], Wb3[i * COUTn + o], s3);
        }
        wcin [(b * KCn + kk) * CINn  + o] = sigmoid_(s1);
        wcout[(b * KCn + kk) * COUTn + o] = sigmoid_(s2);
        biasb[(b * KCn + kk) * COUTn + o] = s3;
    } else if (tid < 41){
        int a2 = tid - 32;
        float s = ba[a2];
        #pragma unroll
        for (int i = 0; i < Mn; ++i) s = fmaf(sh.m.kfL[0][i], Wa[i * AREAn + a2], s);
        warea[(b * KCn + kk) * AREAn + a2] = sigmoid_(s);
    }
}

// ---------------------------------------------------------------------------
// K2: grouped matmul over fixed 32-pixel tiles of the sorted array (perfect
// balance). Per segment (cluster run): build modulated kernel in LDS (div-free
// 36-elem mapping), 2x2 register-tiled fp32 matmul, masked writes.
// ---------------------------------------------------------------------------
__global__ __launch_bounds__(256) void k_out(const float* __restrict__ x,
                                             const int* __restrict__ sorted,
                                             const int* __restrict__ idx,
                                             const float* __restrict__ wcin,
                                             const float* __restrict__ warea,
                                             const float* __restrict__ wcout,
                                             const float* __restrict__ biasb,
                                             const float* __restrict__ kern0,
                                             float* __restrict__ out){
    int b    = blockIdx.x >> 7;
    int tile = blockIdx.x & 127;
    int tid  = threadIdx.x;

    __shared__ float kernT[KCn * LDK];
    __shared__ float patchL[32 * LDK];
    __shared__ int   pix[32];
    __shared__ int   kid[32];
    __shared__ float wcl[CINn], wal[AREAn], wol[COUTn], biasL[COUTn];

    if (tid < 32){
        int pp = sorted[b * Sn + tile * 32 + tid];
        pix[tid] = pp;
        kid[tid] = idx[b * Sn + pp];
    }
    // staging constants (fixed per thread)
    int fA = tid;       int cA = fA / 9, aA = fA - cA * 9;
    int dyA = aA / 3 - 1, dxA = aA % 3 - 1;
    int fB = 256 + tid; int cB = fB / 9, aB = fB - cB * 9;
    int dyB = aB / 3 - 1, dxB = aB % 3 - 1;
    __syncthreads();

    #pragma unroll 4
    for (int px = 0; px < 32; ++px){
        int pp = pix[px];
        int py = pp >> 6, pxx = pp & 63;
        int y1 = py + dyA, x1 = pxx + dxA;
        patchL[px * LDK + tid] = (y1 >= 0 && y1 < Hn && x1 >= 0 && x1 < Wn)
            ? x[((size_t)(b * CINn + cA) << 12) + (y1 << 6) + x1] : 0.f;
        if (tid < 32){
            int y2 = py + dyB, x2 = pxx + dxB;
            patchL[px * LDK + 256 + tid] = (y2 >= 0 && y2 < Hn && x2 >= 0 && x2 < Wn)
                ? x[((size_t)(b * CINn + cB) << 12) + (y2 << 6) + x2] : 0.f;
        }
    }

    int o2 = tid & 15, p2 = tid >> 4;
    int oA = o2 * 2, oB = o2 * 2 + 1;
    int pxA = p2 * 2, pxB = p2 * 2 + 1;

    int i0 = 0;
    while (i0 < 32){
        __syncthreads();                    // protect kernT/vecs from prev segment
        int kcur = kid[i0];
        int i1 = i0 + 1;
        while (i1 < 32 && kid[i1] == kcur) ++i1;

        if (tid < 32)       wcl[tid]        = wcin [(b * KCn + kcur) * CINn  + tid];
        else if (tid < 64)  wol[tid - 32]   = wcout[(b * KCn + kcur) * COUTn + tid - 32];
        else if (tid < 73)  wal[tid - 64]   = warea[(b * KCn + kcur) * AREAn + tid - 64];
        else if (tid >= 96 && tid < 128) biasL[tid - 96] = biasb[(b * KCn + kcur) * COUTn + tid - 96];
        __syncthreads();

        {   // build modulated kernel: thread -> (o = tid>>3, 36 contiguous f)
            int o  = tid >> 3;
            int q  = tid & 7;
            int f0 = q * 36;
            int cc = q * 4, aa = 0;
            float wo_ = wol[o];
            float* kr = kernT + o * LDK + f0;
            #pragma unroll 4
            for (int i2 = 0; i2 < 36; ++i2){
                kr[i2] = wcl[cc] * wal[aa] * wo_ * kern0[(f0 + i2) * COUTn + o];
                if (++aa == 9){ aa = 0; ++cc; }
            }
        }
        __syncthreads();

        bool actA = (pxA >= i0 && pxA < i1);
        bool actB = (pxB >= i0 && pxB < i1);
        if (actA || actB){
            const float* krA = kernT + oA * LDK;
            const float* krB = kernT + oB * LDK;
            const float* prA = patchL + pxA * LDK;
            const float* prB = patchL + pxB * LDK;
            float s00 = 0.f, s01 = 0.f, s10 = 0.f, s11 = 0.f;
            if (actA && actB){
                #pragma unroll 4
                for (int fq = 0; fq < Fn; fq += 4){
                    float4 k0 = *reinterpret_cast<const float4*>(krA + fq);
                    float4 k1 = *reinterpret_cast<const float4*>(krB + fq);
                    float4 pa = *reinterpret_cast<const float4*>(prA + fq);
                    float4 pb = *reinterpret_cast<const float4*>(prB + fq);
                    s00 = fmaf(pa.x,k0.x,s00); s00 = fmaf(pa.y,k0.y,s00); s00 = fmaf(pa.z,k0.z,s00); s00 = fmaf(pa.w,k0.w,s00);
                    s01 = fmaf(pa.x,k1.x,s01); s01 = fmaf(pa.y,k1.y,s01); s01 = fmaf(pa.z,k1.z,s01); s01 = fmaf(pa.w,k1.w,s01);
                    s10 = fmaf(pb.x,k0.x,s10); s10 = fmaf(pb.y,k0.y,s10); s10 = fmaf(pb.z,k0.z,s10); s10 = fmaf(pb.w,k0.w,s10);
                    s11 = fmaf(pb.x,k1.x,s11); s11 = fmaf(pb.y,k1.y,s11); s11 = fmaf(pb.z,k1.z,s11); s11 = fmaf(pb.w,k1.w,s11);
                }
            } else {
                const float* pr = actA ? prA : prB;
                #pragma unroll 4
                for (int fq = 0; fq < Fn; fq += 4){
                    float4 k0 = *reinterpret_cast<const float4*>(krA + fq);
                    float4 k1 = *reinterpret_cast<const float4*>(krB + fq);
                    float4 pa = *reinterpret_cast<const float4*>(pr + fq);
                    s00 = fmaf(pa.x,k0.x,s00); s00 = fmaf(pa.y,k0.y,s00); s00 = fmaf(pa.z,k0.z,s00); s00 = fmaf(pa.w,k0.w,s00);
                    s01 = fmaf(pa.x,k1.x,s01); s01 = fmaf(pa.y,k1.y,s01); s01 = fmaf(pa.z,k1.z,s01); s01 = fmaf(pa.w,k1.w,s01);
                }
                if (actB){ s10 = s00; s11 = s01; s00 = 0.f; s01 = 0.f; }
            }
            if (actA){
                int pp = pix[pxA];
                out[((size_t)(b * COUTn + oA) << 12) + pp] = biasL[oA] + s00;
                out[((size_t)(b * COUTn + oB) << 12) + pp] = biasL[oB] + s01;
            }
            if (actB){
                int pp = pix[pxB];
                out[((size_t)(b * COUTn + oA) << 12) + pp] = biasL[oA] + s10;
                out[((size_t)(b * COUTn + oB) << 12) + pp] = biasL[oB] + s11;
            }
        }
        i0 = i1;
    }
}

// ---------------------------------------------------------------------------
extern "C" void kernel_launch(void* const* d_in, const int* in_sizes, int n_in,
                              void* d_out, int out_size, void* d_ws, size_t ws_size,
                              hipStream_t stream){
    const float* x    = (const float*)d_in[0];
    const float* Wh1  = (const float*)d_in[1];
    const float* bh1  = (const float*)d_in[2];
    const float* Wh2  = (const float*)d_in[3];
    const float* bh2  = (const float*)d_in[4];
    const float* Wa   = (const float*)d_in[5];
    const float* ba   = (const float*)d_in[6];
    const float* Wc   = (const float*)d_in[7];
    const float* bc   = (const float*)d_in[8];
    const float* Wo   = (const float*)d_in[9];
    const float* bo   = (const float*)d_in[10];
    const float* kern0= (const float*)d_in[11];
    const float* Wb1  = (const float*)d_in[12];
    const float* bb1  = (const float*)d_in[13];
    const float* Wb2  = (const float*)d_in[14];
    const float* bb2  = (const float*)d_in[15];
    const float* Wb3  = (const float*)d_in[16];
    const float* bb3  = (const float*)d_in[17];

    char* ws = (char*)d_ws;
    float*    feat   = (float*)(ws + 0);             // 2,097,152
    u64*      gsum   = (u64*)  (ws + 2097152);       //    98,304
    unsigned* gcnt   = (unsigned*)(ws + 2195456);    //     1,536
    float*    gcent  = (float*)(ws + 2196992);       //    16,384
    int*      idx    = (int*)  (ws + 2213376);       //    65,536
    int*      sorted = (int*)  (ws + 2278912);       //    65,536
    int*      offs   = (int*)  (ws + 2344448);       //     1,024 (pad)
    float*    wcin   = (float*)(ws + 2345472);       //    16,384
    float*    warea  = (float*)(ws + 2361856);       //     4,608
    float*    wcout  = (float*)(ws + 2366464);       //    16,384
    float*    biasb  = (float*)(ws + 2382848);       //    16,384
    unsigned* bars   = (unsigned*)(ws + 2399232);    //       512

    float* outp = (float*)d_out;
    float* idxf = outp + (size_t)Bn * COUTn * Sn;

    k_init<<<(Bn * CINn * Sn) / 256, 256, 0, stream>>>(x, feat, gsum, gcnt, bars);
    k_main<<<Bn * NBLK_B, 256, 0, stream>>>(x, feat, gcent, gsum, gcnt, idx, idxf,
                                            sorted, offs,
                                            Wh1, bh1, Wh2, bh2, Wa, ba, Wc, bc, Wo, bo,
                                            Wb1, bb1, Wb2, bb2, Wb3, bb3,
                                            wcin, warea, wcout, biasb, bars);
    k_out<<<Bn * 128, 256, 0, stream>>>(x, sorted, idx, wcin, warea, wcout, biasb,
                                        kern0, outp);
}

// Round 3
// 273.350 us; speedup vs baseline: 1.1288x; 1.1288x over previous
//
#include <hip/hip_runtime.h>
#include <stdint.h>

typedef unsigned long long u64;

#define Bn 4
#define CINn 32
#define Hn 64
#define Wn 64
#define Sn 4096
#define KCn 32
#define Mn 16
#define COUTn 32
#define AREAn 9
#define Fn 288
#define NITER 10
#define FXSCALE 4294967296.0
#define NBLK_B 32          // k_main blocks per batch
#define LDK 292            // padded LDS row stride (floats) in k_out

// Relaxed agent-scope atomics: coherent (bypass non-coherent L1/L2 via sc
// flags) but NO cache-maintenance ops (no buffer_inv / buffer_wbl2).
#define AT_LD_U32(p)    __hip_atomic_load((p),  __ATOMIC_RELAXED, __HIP_MEMORY_SCOPE_AGENT)
#define AT_LD_U64(p)    __hip_atomic_load((p),  __ATOMIC_RELAXED, __HIP_MEMORY_SCOPE_AGENT)
#define AT_ST_U32(p,v)  __hip_atomic_store((p), (v), __ATOMIC_RELAXED, __HIP_MEMORY_SCOPE_AGENT)
#define AT_ST_U64(p,v)  __hip_atomic_store((p), (v), __ATOMIC_RELAXED, __HIP_MEMORY_SCOPE_AGENT)

static __device__ __forceinline__ float relu_(float v){ return v > 0.f ? v : 0.f; }
static __device__ __forceinline__ float sigmoid_(float v){ return 1.f / (1.f + expf(-v)); }

// ---------------------------------------------------------------------------
// Per-batch software barrier (32 blocks). RELAXED spin (no per-poll L2 inv);
// RELEASE only on the arrive-add (orders prior coherent stores/atomics);
// one ACQUIRE load on exit. All cross-block data uses coherent atomics, so
// no full-cache flushes are ever needed.
// ---------------------------------------------------------------------------
static __device__ __forceinline__ void batch_barrier(unsigned* bar){
    __syncthreads();
    if (threadIdx.x == 0){
        unsigned* cnt = bar;
        unsigned* gen = bar + 16;
        unsigned g = __hip_atomic_load(gen, __ATOMIC_RELAXED, __HIP_MEMORY_SCOPE_AGENT);
        unsigned a = __hip_atomic_fetch_add(cnt, 1u, __ATOMIC_RELEASE, __HIP_MEMORY_SCOPE_AGENT);
        if (a == (unsigned)(NBLK_B - 1)){
            __hip_atomic_store(cnt, 0u, __ATOMIC_RELAXED, __HIP_MEMORY_SCOPE_AGENT);
            __hip_atomic_fetch_add(gen, 1u, __ATOMIC_RELEASE, __HIP_MEMORY_SCOPE_AGENT);
        } else {
            while (__hip_atomic_load(gen, __ATOMIC_RELAXED, __HIP_MEMORY_SCOPE_AGENT) == g)
                __builtin_amdgcn_s_sleep(2);
            (void)__hip_atomic_load(gen, __ATOMIC_ACQUIRE, __HIP_MEMORY_SCOPE_AGENT);
        }
    }
    __syncthreads();
}

// ---------------------------------------------------------------------------
// K0: feat = 3x3 mean; zero fixed-point accumulators + barrier state.
// ---------------------------------------------------------------------------
__global__ __launch_bounds__(256) void k_init(const float* __restrict__ x,
                                              float* __restrict__ feat,
                                              u64* __restrict__ gsum,
                                              unsigned* __restrict__ gcnt,
                                              unsigned* __restrict__ bar){
    int g = blockIdx.x * 256 + threadIdx.x;
    if (g < 3 * Bn * KCn * CINn) gsum[g] = 0ull;
    if (g < 3 * Bn * KCn)        gcnt[g] = 0u;
    if (g < 4 * 32)              bar[g]  = 0u;
    int p = g & (Sn - 1);
    int c = (g >> 12) & (CINn - 1);
    int b = g >> 17;
    int y = p >> 6, xx = p & 63;
    const float* xc = x + ((size_t)(b * CINn + c) << 12);
    float s = 0.f;
    #pragma unroll
    for (int i = 0; i < 3; ++i){
        int yy = y + i - 1;
        if (yy < 0 || yy >= Hn) continue;
        #pragma unroll
        for (int j = 0; j < 3; ++j){
            int xj = xx + j - 1;
            if (xj < 0 || xj >= Wn) continue;
            s += xc[(yy << 6) + xj];
        }
    }
    feat[g] = s * (1.f / 9.f);
}

// ---------------------------------------------------------------------------
// K1: fused pipeline. Grid = 128 blocks (4 batches x 32), 256 threads.
// ---------------------------------------------------------------------------
struct AssignSh {
    u64   fxL[128][32];       // 32 KiB, persists across iterations
    float cent[KCn][CINn];    // persists across iterations (empty-cluster keep)
    float c2[KCn];
    float bestd[256];
    int   bestk[256];
    unsigned cnt32[KCn];
    unsigned cntPrev[KCn];
    unsigned base32[KCn + 1];
    unsigned scat[KCn];
    int   plist[128];
    int   rankF[128];
    unsigned totK[KCn];
    unsigned goffK[KCn + 1];
    unsigned baseBT[KCn];
};
struct SmkSh {
    float centL[Fn];
    int   pl[256];
    float part1[16][16], part2[16][16];
    float hL[2][Mn];
    float kfL[2][Mn];
};
union ShU { AssignSh a; SmkSh m; };

__global__ __launch_bounds__(256) void k_main(const float* __restrict__ x,
        const float* __restrict__ feat,
        u64* __restrict__ gsum, unsigned* __restrict__ gcnt,
        unsigned* __restrict__ blkcnt,
        int* __restrict__ idx, float* __restrict__ idxf,
        int* __restrict__ sorted,
        const float* __restrict__ Wh1, const float* __restrict__ bh1,
        const float* __restrict__ Wh2, const float* __restrict__ bh2,
        const float* __restrict__ Wa,  const float* __restrict__ ba,
        const float* __restrict__ Wc,  const float* __restrict__ bc,
        const float* __restrict__ Wo,  const float* __restrict__ bo,
        const float* __restrict__ Wb1, const float* __restrict__ bb1,
        const float* __restrict__ Wb2, const float* __restrict__ bb2,
        const float* __restrict__ Wb3, const float* __restrict__ bb3,
        float* __restrict__ wcin, float* __restrict__ warea,
        float* __restrict__ wcout, float* __restrict__ biasb,
        unsigned* __restrict__ bars){
    __shared__ ShU sh;
    const int tid  = threadIdx.x;
    const int b    = blockIdx.x >> 5;
    const int tnum = blockIdx.x & 31;
    unsigned* bar  = bars + b * 32;

    const int pxi  = tid & 127;
    const int half = tid >> 7;
    const int p    = tnum * 128 + pxi;

    float fv[CINn];
    #pragma unroll
    for (int c = 0; c < CINn; ++c) fv[c] = feat[(b * CINn + c) * Sn + p];
    float f2 = 0.f;
    #pragma unroll
    for (int c = 0; c < CINn; ++c) f2 = fmaf(fv[c], fv[c], f2);
    if (tid < 128){
        #pragma unroll
        for (int c = 0; c < CINn; ++c)
            sh.a.fxL[tid][c] = (u64)llrint((double)fv[c] * FXSCALE);
    }

    // ---------------- KMeans iterations ----------------
    for (int iter = 0; iter <= NITER; ++iter){
        const int prev = (iter + 2) % 3;
        const int cur  = iter % 3;
        const int nxt  = (iter + 1) % 3;

        if (iter > 0 && tid < KCn)
            sh.a.cntPrev[tid] = AT_LD_U32(&gcnt[(prev * Bn + b) * KCn + tid]);
        __syncthreads();

        for (int e = tid; e < KCn * CINn; e += 256){
            int k = e >> 5, c = e & 31;
            if (iter == 0){
                sh.a.cent[k][c] = feat[(b * CINn + c) * Sn + k * (Sn / KCn)];
            } else {
                unsigned cn = sh.a.cntPrev[k];
                if (cn > 0){
                    u64 sv = AT_LD_U64(&gsum[((prev * Bn + b) * KCn + k) * CINn + c]);
                    sh.a.cent[k][c] = (float)((double)(long long)sv / ((double)cn * FXSCALE));
                }
                // else: keep previous centroid (already in LDS)
            }
            if (tnum == 0)
                AT_ST_U64(&gsum[((nxt * Bn + b) * KCn + k) * CINn + c], 0ull);
        }
        if (tnum == 0 && tid < KCn)
            AT_ST_U32(&gcnt[(nxt * Bn + b) * KCn + tid], 0u);
        __syncthreads();

        if (tid < 32){
            float s = 0.f;
            #pragma unroll
            for (int c = 0; c < CINn; ++c) s = fmaf(sh.a.cent[tid][c], sh.a.cent[tid][c], s);
            sh.a.c2[tid] = s;
        } else if (tid < 64){
            sh.a.cnt32[tid - 32] = 0u;
        } else if (tid < 96){
            sh.a.scat[tid - 64] = 0u;
        }
        __syncthreads();

        // dot over this thread's k-half (float4 LDS reads)
        float best = 3.402823466e38f;
        int   bk   = half << 4;
        #pragma unroll 4
        for (int k = 0; k < 16; ++k){
            const int kk = (half << 4) + k;
            const float4* cr4 = reinterpret_cast<const float4*>(sh.a.cent[kk]);
            float dot = 0.f;
            #pragma unroll
            for (int cq = 0; cq < 8; ++cq){
                float4 cv = cr4[cq];
                dot = fmaf(fv[cq * 4 + 0], cv.x, dot);
                dot = fmaf(fv[cq * 4 + 1], cv.y, dot);
                dot = fmaf(fv[cq * 4 + 2], cv.z, dot);
                dot = fmaf(fv[cq * 4 + 3], cv.w, dot);
            }
            float d = f2 - 2.f * dot + sh.a.c2[kk];
            if (d < best){ best = d; bk = kk; }   // strict < = first-min
        }
        sh.a.bestd[tid] = best;
        sh.a.bestk[tid] = bk;
        __syncthreads();

        int bi = -1;
        if (tid < 128){
            float d0 = sh.a.bestd[tid], d1 = sh.a.bestd[tid + 128];
            int   k0 = sh.a.bestk[tid], k1 = sh.a.bestk[tid + 128];
            bi = (d1 < d0) ? k1 : k0;             // tie -> lower-k half
            if (iter < NITER) atomicAdd(&sh.a.cnt32[bi], 1u);
        }

        if (iter < NITER){
            __syncthreads();
            if (tid == 0){
                unsigned acc = 0;
                #pragma unroll
                for (int k = 0; k < KCn; ++k){ sh.a.base32[k] = acc; acc += sh.a.cnt32[k]; }
            }
            __syncthreads();
            if (tid < 128){
                unsigned pos = sh.a.base32[bi] + atomicAdd(&sh.a.scat[bi], 1u);
                sh.a.plist[pos] = tid;
            }
            __syncthreads();
            {   // per-(k, 4-channel-group) order-independent integer sums
                const int k  = tid >> 3;
                const int cg = (tid & 7) * 4;
                const unsigned s0 = sh.a.base32[k];
                const unsigned nk = sh.a.cnt32[k];
                u64 a0 = 0, a1 = 0, a2 = 0, a3 = 0;
                for (unsigned i = 0; i < nk; ++i){
                    int px = sh.a.plist[s0 + i];
                    a0 += sh.a.fxL[px][cg + 0];
                    a1 += sh.a.fxL[px][cg + 1];
                    a2 += sh.a.fxL[px][cg + 2];
                    a3 += sh.a.fxL[px][cg + 3];
                }
                u64* gs = &gsum[((cur * Bn + b) * KCn + k) * CINn + cg];
                if (a0) atomicAdd(gs + 0, a0);
                if (a1) atomicAdd(gs + 1, a1);
                if (a2) atomicAdd(gs + 2, a2);
                if (a3) atomicAdd(gs + 3, a3);
                if ((tid & 7) == 0 && nk) atomicAdd(&gcnt[(cur * Bn + b) * KCn + k], nk);
            }
        } else {
            if (tid < 128){
                idx [b * Sn + p] = bi;            // plain: consumed by k_out (cross-kernel)
                idxf[b * Sn + p] = (float)bi;     // plain: output
                sh.a.bestk[tid]  = bi;            // final assignment for local sort
            }
        }
        batch_barrier(bar);
    }

    // ---------------- distributed stable sort ----------------
    // stable ranks within block (integer, deterministic), publish counts
    if (tid < KCn){
        int r = 0;
        for (int q = 0; q < 128; ++q)
            if (sh.a.bestk[q] == tid) sh.a.rankF[q] = r++;
        sh.a.cnt32[tid] = (unsigned)r;
        AT_ST_U32(&blkcnt[(b * KCn + tid) * NBLK_B + tnum], (unsigned)r);
    }
    batch_barrier(bar);

    // cross-block offsets: thread k scans the 32 per-block counts
    if (tid < KCn){
        unsigned run = 0, mybase = 0;
        #pragma unroll 4
        for (int t2 = 0; t2 < NBLK_B; ++t2){
            unsigned v = AT_LD_U32(&blkcnt[(b * KCn + tid) * NBLK_B + t2]);
            if (t2 == tnum) mybase = run;
            run += v;
        }
        sh.a.totK[tid]   = run;
        sh.a.baseBT[tid] = mybase;
    }
    __syncthreads();
    if (tid == 0){
        unsigned acc = 0;
        #pragma unroll
        for (int k = 0; k < KCn; ++k){ sh.a.goffK[k] = acc; acc += sh.a.totK[k]; }
        sh.a.goffK[KCn] = acc;
    }
    __syncthreads();
    if (tid < 128){
        int k = sh.a.bestk[tid];
        unsigned pos = sh.a.goffK[k] + sh.a.baseBT[k] + (unsigned)sh.a.rankF[tid];
        AT_ST_U32((unsigned*)&sorted[b * Sn + pos], (unsigned)(tnum * 128 + tid));
    }
    const int kk    = tnum;
    const int off0r = (int)sh.a.goffK[kk];
    const int nmy   = (int)sh.a.totK[kk];
    batch_barrier(bar);

    // ---------------- segmean (cluster kk = tnum) ----------------
    {
        int fA = tid;           int cA = fA / 9, aA = fA - cA * 9;
        int dyA = aA / 3 - 1,   dxA = aA % 3 - 1;
        int fB = 256 + tid;     int cB = fB / 9, aB = fB - cB * 9;
        int dyB = aB / 3 - 1,   dxB = aB % 3 - 1;
        float sumA = 0.f, sumB = 0.f;
        for (int base = 0; base < nmy; base += 256){
            int m = min(256, nmy - base);
            __syncthreads();
            if (tid < m) sh.m.pl[tid] = (int)AT_LD_U32((unsigned*)&sorted[b * Sn + off0r + base + tid]);
            __syncthreads();
            for (int i = 0; i < m; ++i){
                int pp = sh.m.pl[i];
                int py = pp >> 6, px2 = pp & 63;
                int y1 = py + dyA, x1 = px2 + dxA;
                float v = (y1 >= 0 && y1 < Hn && x1 >= 0 && x1 < Wn)
                          ? x[((size_t)(b * CINn + cA) << 12) + (y1 << 6) + x1] : 0.f;
                sumA += v;
                if (tid < 32){
                    int y2 = py + dyB, x2 = px2 + dxB;
                    float v2 = (y2 >= 0 && y2 < Hn && x2 >= 0 && x2 < Wn)
                               ? x[((size_t)(b * CINn + cB) << 12) + (y2 << 6) + x2] : 0.f;
                    sumB += v2;
                }
            }
        }
        __syncthreads();
        sh.m.centL[fA] = sumA / (float)max(nmy, 1);
        if (tid < 32) sh.m.centL[fB] = sumB / (float)max(nmy, 1);
    }
    __syncthreads();

    // ---------------- MLPs + heads ----------------
    {
        int j = tid & 15, rep = tid >> 4;
        float p1 = 0.f, p2 = 0.f;
        int fbeg = rep * 18;
        for (int ff = fbeg; ff < fbeg + 18; ++ff){
            float cv = sh.m.centL[ff];
            p1 = fmaf(cv, Wh1[ff * Mn + j], p1);
            p2 = fmaf(cv, Wb1[ff * Mn + j], p2);
        }
        sh.m.part1[rep][j] = p1;
        sh.m.part2[rep][j] = p2;
    }
    __syncthreads();
    if (tid < 32){
        int br = tid >> 4, j = tid & 15;
        float s = br ? bb1[j] : bh1[j];
        for (int r = 0; r < 16; ++r) s += br ? sh.m.part2[r][j] : sh.m.part1[r][j];
        sh.m.hL[br][j] = relu_(s);
    }
    __syncthreads();
    if (tid < 32){
        int br = tid >> 4, j = tid & 15;
        const float* W2 = br ? Wb2 : Wh2;
        float s = br ? bb2[j] : bh2[j];
        #pragma unroll
        for (int i = 0; i < Mn; ++i) s = fmaf(sh.m.hL[br][i], W2[i * Mn + j], s);
        sh.m.kfL[br][j] = relu_(s);
    }
    __syncthreads();
    if (tid < 32){
        int o = tid;
        float s1 = bc[o], s2 = bo[o], s3 = bb3[o];
        #pragma unroll
        for (int i = 0; i < Mn; ++i){
            float kv = sh.m.kfL[0][i];
            s1 = fmaf(kv, Wc[i * COUTn + o], s1);
            s2 = fmaf(kv, Wo[i * COUTn + o], s2);
            s3 = fmaf(sh.m.kfL[1][i], Wb3[i * COUTn + o], s3);
        }
        wcin [(b * KCn + kk) * CINn  + o] = sigmoid_(s1);
        wcout[(b * KCn + kk) * COUTn + o] = sigmoid_(s2);
        biasb[(b * KCn + kk) * COUTn + o] = s3;
    } else if (tid < 41){
        int a2 = tid - 32;
        float s = ba[a2];
        #pragma unroll
        for (int i = 0; i < Mn; ++i) s = fmaf(sh.m.kfL[0][i], Wa[i * AREAn + a2], s);
        warea[(b * KCn + kk) * AREAn + a2] = sigmoid_(s);
    }
}

// ---------------------------------------------------------------------------
// K2: grouped matmul over fixed 32-pixel tiles of the sorted array.
// ---------------------------------------------------------------------------
__global__ __launch_bounds__(256) void k_out(const float* __restrict__ x,
                                             const int* __restrict__ sorted,
                                             const int* __restrict__ idx,
                                             const float* __restrict__ wcin,
                                             const float* __restrict__ warea,
                                             const float* __restrict__ wcout,
                                             const float* __restrict__ biasb,
                                             const float* __restrict__ kern0,
                                             float* __restrict__ out){
    int b    = blockIdx.x >> 7;
    int tile = blockIdx.x & 127;
    int tid  = threadIdx.x;

    __shared__ float kernT[KCn * LDK];
    __shared__ float patchL[32 * LDK];
    __shared__ int   pix[32];
    __shared__ int   kid[32];
    __shared__ float wcl[CINn], wal[AREAn], wol[COUTn], biasL[COUTn];

    if (tid < 32){
        int pp = sorted[b * Sn + tile * 32 + tid];
        pix[tid] = pp;
        kid[tid] = idx[b * Sn + pp];
    }
    int fA = tid;       int cA = fA / 9, aA = fA - cA * 9;
    int dyA = aA / 3 - 1, dxA = aA % 3 - 1;
    int fB = 256 + tid; int cB = fB / 9, aB = fB - cB * 9;
    int dyB = aB / 3 - 1, dxB = aB % 3 - 1;
    __syncthreads();

    #pragma unroll 4
    for (int px = 0; px < 32; ++px){
        int pp = pix[px];
        int py = pp >> 6, pxx = pp & 63;
        int y1 = py + dyA, x1 = pxx + dxA;
        patchL[px * LDK + tid] = (y1 >= 0 && y1 < Hn && x1 >= 0 && x1 < Wn)
            ? x[((size_t)(b * CINn + cA) << 12) + (y1 << 6) + x1] : 0.f;
        if (tid < 32){
            int y2 = py + dyB, x2 = pxx + dxB;
            patchL[px * LDK + 256 + tid] = (y2 >= 0 && y2 < Hn && x2 >= 0 && x2 < Wn)
                ? x[((size_t)(b * CINn + cB) << 12) + (y2 << 6) + x2] : 0.f;
        }
    }

    int o2 = tid & 15, p2 = tid >> 4;
    int oA = o2 * 2, oB = o2 * 2 + 1;
    int pxA = p2 * 2, pxB = p2 * 2 + 1;

    int i0 = 0;
    while (i0 < 32){
        __syncthreads();
        int kcur = kid[i0];
        int i1 = i0 + 1;
        while (i1 < 32 && kid[i1] == kcur) ++i1;

        if (tid < 32)       wcl[tid]        = wcin [(b * KCn + kcur) * CINn  + tid];
        else if (tid < 64)  wol[tid - 32]   = wcout[(b * KCn + kcur) * COUTn + tid - 32];
        else if (tid < 73)  wal[tid - 64]   = warea[(b * KCn + kcur) * AREAn + tid - 64];
        else if (tid >= 96 && tid < 128) biasL[tid - 96] = biasb[(b * KCn + kcur) * COUTn + tid - 96];
        __syncthreads();

        {
            int o  = tid >> 3;
            int q  = tid & 7;
            int f0 = q * 36;
            int cc = q * 4, aa = 0;
            float wo_ = wol[o];
            float* kr = kernT + o * LDK + f0;
            #pragma unroll 4
            for (int i2 = 0; i2 < 36; ++i2){
                kr[i2] = wcl[cc] * wal[aa] * wo_ * kern0[(f0 + i2) * COUTn + o];
                if (++aa == 9){ aa = 0; ++cc; }
            }
        }
        __syncthreads();

        bool actA = (pxA >= i0 && pxA < i1);
        bool actB = (pxB >= i0 && pxB < i1);
        if (actA || actB){
            const float* krA = kernT + oA * LDK;
            const float* krB = kernT + oB * LDK;
            const float* prA = patchL + pxA * LDK;
            const float* prB = patchL + pxB * LDK;
            float s00 = 0.f, s01 = 0.f, s10 = 0.f, s11 = 0.f;
            if (actA && actB){
                #pragma unroll 4
                for (int fq = 0; fq < Fn; fq += 4){
                    float4 k0 = *reinterpret_cast<const float4*>(krA + fq);
                    float4 k1 = *reinterpret_cast<const float4*>(krB + fq);
                    float4 pa = *reinterpret_cast<const float4*>(prA + fq);
                    float4 pb = *reinterpret_cast<const float4*>(prB + fq);
                    s00 = fmaf(pa.x,k0.x,s00); s00 = fmaf(pa.y,k0.y,s00); s00 = fmaf(pa.z,k0.z,s00); s00 = fmaf(pa.w,k0.w,s00);
                    s01 = fmaf(pa.x,k1.x,s01); s01 = fmaf(pa.y,k1.y,s01); s01 = fmaf(pa.z,k1.z,s01); s01 = fmaf(pa.w,k1.w,s01);
                    s10 = fmaf(pb.x,k0.x,s10); s10 = fmaf(pb.y,k0.y,s10); s10 = fmaf(pb.z,k0.z,s10); s10 = fmaf(pb.w,k0.w,s10);
                    s11 = fmaf(pb.x,k1.x,s11); s11 = fmaf(pb.y,k1.y,s11); s11 = fmaf(pb.z,k1.z,s11); s11 = fmaf(pb.w,k1.w,s11);
                }
            } else {
                const float* pr = actA ? prA : prB;
                #pragma unroll 4
                for (int fq = 0; fq < Fn; fq += 4){
                    float4 k0 = *reinterpret_cast<const float4*>(krA + fq);
                    float4 k1 = *reinterpret_cast<const float4*>(krB + fq);
                    float4 pa = *reinterpret_cast<const float4*>(pr + fq);
                    s00 = fmaf(pa.x,k0.x,s00); s00 = fmaf(pa.y,k0.y,s00); s00 = fmaf(pa.z,k0.z,s00); s00 = fmaf(pa.w,k0.w,s00);
                    s01 = fmaf(pa.x,k1.x,s01); s01 = fmaf(pa.y,k1.y,s01); s01 = fmaf(pa.z,k1.z,s01); s01 = fmaf(pa.w,k1.w,s01);
                }
                if (actB){ s10 = s00; s11 = s01; s00 = 0.f; s01 = 0.f; }
            }
            if (actA){
                int pp = pix[pxA];
                out[((size_t)(b * COUTn + oA) << 12) + pp] = biasL[oA] + s00;
                out[((size_t)(b * COUTn + oB) << 12) + pp] = biasL[oB] + s01;
            }
            if (actB){
                int pp = pix[pxB];
                out[((size_t)(b * COUTn + oA) << 12) + pp] = biasL[oA] + s10;
                out[((size_t)(b * COUTn + oB) << 12) + pp] = biasL[oB] + s11;
            }
        }
        i0 = i1;
    }
}

// ---------------------------------------------------------------------------
extern "C" void kernel_launch(void* const* d_in, const int* in_sizes, int n_in,
                              void* d_out, int out_size, void* d_ws, size_t ws_size,
                              hipStream_t stream){
    const float* x    = (const float*)d_in[0];
    const float* Wh1  = (const float*)d_in[1];
    const float* bh1  = (const float*)d_in[2];
    const float* Wh2  = (const float*)d_in[3];
    const float* bh2  = (const float*)d_in[4];
    const float* Wa   = (const float*)d_in[5];
    const float* ba   = (const float*)d_in[6];
    const float* Wc   = (const float*)d_in[7];
    const float* bc   = (const float*)d_in[8];
    const float* Wo   = (const float*)d_in[9];
    const float* bo   = (const float*)d_in[10];
    const float* kern0= (const float*)d_in[11];
    const float* Wb1  = (const float*)d_in[12];
    const float* bb1  = (const float*)d_in[13];
    const float* Wb2  = (const float*)d_in[14];
    const float* bb2  = (const float*)d_in[15];
    const float* Wb3  = (const float*)d_in[16];
    const float* bb3  = (const float*)d_in[17];

    char* ws = (char*)d_ws;
    float*    feat   = (float*)(ws + 0);             // 2,097,152
    u64*      gsum   = (u64*)  (ws + 2097152);       //    98,304
    unsigned* gcnt   = (unsigned*)(ws + 2195456);    //     1,536
    unsigned* blkcnt = (unsigned*)(ws + 2196992);    //    16,384
    int*      idx    = (int*)  (ws + 2213376);       //    65,536
    int*      sorted = (int*)  (ws + 2278912);       //    65,536
    float*    wcin   = (float*)(ws + 2344448);       //    16,384
    float*    warea  = (float*)(ws + 2360832);       //     4,608
    float*    wcout  = (float*)(ws + 2365440);       //    16,384
    float*    biasb  = (float*)(ws + 2381824);       //    16,384
    unsigned* bars   = (unsigned*)(ws + 2398208);    //       512

    float* outp = (float*)d_out;
    float* idxf = outp + (size_t)Bn * COUTn * Sn;

    k_init<<<(Bn * CINn * Sn) / 256, 256, 0, stream>>>(x, feat, gsum, gcnt, bars);
    k_main<<<Bn * NBLK_B, 256, 0, stream>>>(x, feat, gsum, gcnt, blkcnt, idx, idxf,
                                            sorted,
                                            Wh1, bh1, Wh2, bh2, Wa, ba, Wc, bc, Wo, bo,
                                            Wb1, bb1, Wb2, bb2, Wb3, bb3,
                                            wcin, warea, wcout, biasb, bars);
    k_out<<<Bn * 128, 256, 0, stream>>>(x, sorted, idx, wcin, warea, wcout, biasb,
                                        kern0, outp);
}

// Round 4
// 225.516 us; speedup vs baseline: 1.3682x; 1.2121x over previous
//
#include <hip/hip_runtime.h>
#include <stdint.h>

typedef unsigned long long u64;

#define Bn 4
#define CINn 32
#define Hn 64
#define Wn 64
#define Sn 4096
#define KCn 32
#define Mn 16
#define COUTn 32
#define AREAn 9
#define Fn 288
#define NITER 10
#define FXSCALE 4294967296.0
#define NBLK_B 32          // k_main blocks per batch
#define LDK 292            // padded LDS row stride (floats) in k_out

// Relaxed agent-scope atomics: coherent (complete at the coherence point,
// bypass non-coherent L1/L2) and emit ZERO cache-maintenance ops.
#define AT_LD_U32(p)    __hip_atomic_load((p),  __ATOMIC_RELAXED, __HIP_MEMORY_SCOPE_AGENT)
#define AT_LD_U64(p)    __hip_atomic_load((p),  __ATOMIC_RELAXED, __HIP_MEMORY_SCOPE_AGENT)
#define AT_ST_U32(p,v)  __hip_atomic_store((p), (v), __ATOMIC_RELAXED, __HIP_MEMORY_SCOPE_AGENT)
#define AT_ST_U64(p,v)  __hip_atomic_store((p), (v), __ATOMIC_RELAXED, __HIP_MEMORY_SCOPE_AGENT)

static __device__ __forceinline__ float relu_(float v){ return v > 0.f ? v : 0.f; }
static __device__ __forceinline__ float sigmoid_(float v){ return 1.f / (1.f + expf(-v)); }

// ---------------------------------------------------------------------------
// Per-batch software barrier, ALL-RELAXED (no buffer_inv / buffer_wbl2).
// Correctness: (1) hipcc drains vmcnt(0) at the __syncthreads before arrival,
// so every thread's sc1 stores / atomics are at the coherence point; (2) the
// arrive-add and gen-poll are sc1 ops at the same coherence point; (3) all
// post-barrier cross-block reads use sc1 loads (never stale L2).
// ---------------------------------------------------------------------------
static __device__ __forceinline__ void batch_barrier(unsigned* bar){
    __syncthreads();
    if (threadIdx.x == 0){
        asm volatile("s_waitcnt vmcnt(0)" ::: "memory");
        unsigned* cnt = bar;
        unsigned* gen = bar + 32;   // separate 128B line
        unsigned g = __hip_atomic_load(gen, __ATOMIC_RELAXED, __HIP_MEMORY_SCOPE_AGENT);
        unsigned a = __hip_atomic_fetch_add(cnt, 1u, __ATOMIC_RELAXED, __HIP_MEMORY_SCOPE_AGENT);
        if (a == (unsigned)(NBLK_B - 1)){
            __hip_atomic_store(cnt, 0u, __ATOMIC_RELAXED, __HIP_MEMORY_SCOPE_AGENT);
            __hip_atomic_fetch_add(gen, 1u, __ATOMIC_RELAXED, __HIP_MEMORY_SCOPE_AGENT);
        } else {
            while (__hip_atomic_load(gen, __ATOMIC_RELAXED, __HIP_MEMORY_SCOPE_AGENT) == g)
                __builtin_amdgcn_s_sleep(4);
        }
    }
    __syncthreads();
}

// ---------------------------------------------------------------------------
// K0: feat = 3x3 mean; zero fixed-point accumulators + barrier state.
// ---------------------------------------------------------------------------
__global__ __launch_bounds__(256) void k_init(const float* __restrict__ x,
                                              float* __restrict__ feat,
                                              u64* __restrict__ gsum,
                                              unsigned* __restrict__ gcnt,
                                              unsigned* __restrict__ bar){
    int g = blockIdx.x * 256 + threadIdx.x;
    if (g < 3 * Bn * KCn * CINn) gsum[g] = 0ull;
    if (g < 3 * Bn * KCn)        gcnt[g] = 0u;
    if (g < 4 * 64)              bar[g]  = 0u;
    int p = g & (Sn - 1);
    int c = (g >> 12) & (CINn - 1);
    int b = g >> 17;
    int y = p >> 6, xx = p & 63;
    const float* xc = x + ((size_t)(b * CINn + c) << 12);
    float s = 0.f;
    #pragma unroll
    for (int i = 0; i < 3; ++i){
        int yy = y + i - 1;
        if (yy < 0 || yy >= Hn) continue;
        #pragma unroll
        for (int j = 0; j < 3; ++j){
            int xj = xx + j - 1;
            if (xj < 0 || xj >= Wn) continue;
            s += xc[(yy << 6) + xj];
        }
    }
    feat[g] = s * (1.f / 9.f);
}

// ---------------------------------------------------------------------------
// K1: fused pipeline. Grid = 128 blocks (4 batches x 32), 256 threads.
// ---------------------------------------------------------------------------
struct AssignSh {
    u64   fxL[128][32];       // 32 KiB, persists across iterations
    u64   lsum[KCn][CINn];    //  8 KiB LDS fixed-point buckets
    float cent[KCn][CINn];    //  4 KiB, persists (empty-cluster keep)
    float c2[KCn];
    float bestd[256];
    int   bestk[256];
    int   bi128[128];
    unsigned lcnt[KCn];
    unsigned cntPrev[KCn];
    int   rankF[128];
    unsigned totK[KCn];
    unsigned goffK[KCn + 1];
    unsigned baseBT[KCn];
};
struct SmkSh {
    float psum[KCn][AREAn][8];   // 9.2 KiB slot partials
    float centL[Fn];
    int   pl[256];
    float part1[16][16], part2[16][16];
    float hL[2][Mn];
    float kfL[2][Mn];
};
union ShU { AssignSh a; SmkSh m; };

__global__ __launch_bounds__(256) void k_main(const float* __restrict__ x,
        const float* __restrict__ feat,
        u64* __restrict__ gsum, unsigned* __restrict__ gcnt,
        unsigned* __restrict__ blkcnt,
        int* __restrict__ idx, float* __restrict__ idxf,
        int* __restrict__ sorted,
        const float* __restrict__ Wh1, const float* __restrict__ bh1,
        const float* __restrict__ Wh2, const float* __restrict__ bh2,
        const float* __restrict__ Wa,  const float* __restrict__ ba,
        const float* __restrict__ Wc,  const float* __restrict__ bc,
        const float* __restrict__ Wo,  const float* __restrict__ bo,
        const float* __restrict__ Wb1, const float* __restrict__ bb1,
        const float* __restrict__ Wb2, const float* __restrict__ bb2,
        const float* __restrict__ Wb3, const float* __restrict__ bb3,
        float* __restrict__ wcin, float* __restrict__ warea,
        float* __restrict__ wcout, float* __restrict__ biasb,
        unsigned* __restrict__ bars){
    __shared__ ShU sh;
    const int tid  = threadIdx.x;
    const int b    = blockIdx.x >> 5;
    const int tnum = blockIdx.x & 31;
    unsigned* bar  = bars + b * 64;

    const int pxi  = tid & 127;
    const int half = tid >> 7;
    const int p    = tnum * 128 + pxi;

    float fv[CINn];
    #pragma unroll
    for (int c = 0; c < CINn; ++c) fv[c] = feat[(b * CINn + c) * Sn + p];
    float f2 = 0.f;
    #pragma unroll
    for (int c = 0; c < CINn; ++c) f2 = fmaf(fv[c], fv[c], f2);
    if (tid < 128){
        #pragma unroll
        for (int c = 0; c < CINn; ++c)
            sh.a.fxL[tid][c] = (u64)llrint((double)fv[c] * FXSCALE);
    }

    // ---------------- KMeans iterations ----------------
    for (int iter = 0; iter <= NITER; ++iter){
        const int prev = (iter + 2) % 3;
        const int cur  = iter % 3;
        const int nxt  = (iter + 1) % 3;

        if (iter > 0 && tid < KCn)
            sh.a.cntPrev[tid] = AT_LD_U32(&gcnt[(prev * Bn + b) * KCn + tid]);
        __syncthreads();

        for (int e = tid; e < KCn * CINn; e += 256){
            int k = e >> 5, c = e & 31;
            if (iter == 0){
                sh.a.cent[k][c] = feat[(b * CINn + c) * Sn + k * (Sn / KCn)];
            } else {
                unsigned cn = sh.a.cntPrev[k];
                if (cn > 0){
                    u64 sv = AT_LD_U64(&gsum[((prev * Bn + b) * KCn + k) * CINn + c]);
                    sh.a.cent[k][c] = (float)((double)(long long)sv / ((double)cn * FXSCALE));
                }
            }
            sh.a.lsum[k][c] = 0ull;
            if (tnum == 0)
                AT_ST_U64(&gsum[((nxt * Bn + b) * KCn + k) * CINn + c], 0ull);
        }
        if (tnum == 0 && tid < KCn)
            AT_ST_U32(&gcnt[(nxt * Bn + b) * KCn + tid], 0u);
        __syncthreads();

        if (tid < 32){
            float s = 0.f;
            #pragma unroll
            for (int c = 0; c < CINn; ++c) s = fmaf(sh.a.cent[tid][c], sh.a.cent[tid][c], s);
            sh.a.c2[tid] = s;
        } else if (tid < 64){
            sh.a.lcnt[tid - 32] = 0u;
        }
        __syncthreads();

        // dot over this thread's k-half (wave-uniform float4 LDS broadcasts)
        float best = 3.402823466e38f;
        int   bk   = half << 4;
        #pragma unroll 4
        for (int k = 0; k < 16; ++k){
            const int kk = (half << 4) + k;
            const float4* cr4 = reinterpret_cast<const float4*>(sh.a.cent[kk]);
            float dot = 0.f;
            #pragma unroll
            for (int cq = 0; cq < 8; ++cq){
                float4 cv = cr4[cq];
                dot = fmaf(fv[cq * 4 + 0], cv.x, dot);
                dot = fmaf(fv[cq * 4 + 1], cv.y, dot);
                dot = fmaf(fv[cq * 4 + 2], cv.z, dot);
                dot = fmaf(fv[cq * 4 + 3], cv.w, dot);
            }
            float d = f2 - 2.f * dot + sh.a.c2[kk];
            if (d < best){ best = d; bk = kk; }   // strict < = first-min
        }
        sh.a.bestd[tid] = best;
        sh.a.bestk[tid] = bk;
        __syncthreads();

        if (tid < 128){
            float d0 = sh.a.bestd[tid], d1 = sh.a.bestd[tid + 128];
            int   k0 = sh.a.bestk[tid], k1 = sh.a.bestk[tid + 128];
            int bi = (d1 < d0) ? k1 : k0;         // tie -> lower-k half
            sh.a.bi128[tid] = bi;
            if (iter < NITER) atomicAdd(&sh.a.lcnt[bi], 1u);
        }
        __syncthreads();

        if (iter < NITER){
            // LDS fixed-point bucket adds (order-independent, exact integers)
            {
                const int myk = sh.a.bi128[pxi];
                const int c0  = half << 4;
                #pragma unroll
                for (int c = 0; c < 16; ++c)
                    atomicAdd(&sh.a.lsum[myk][c0 + c], sh.a.fxL[pxi][c0 + c]);
            }
            __syncthreads();
            // publish per-block buckets with device atomics (values exact)
            for (int e = tid; e < KCn * CINn; e += 256){
                int k = e >> 5, c = e & 31;
                u64 v = sh.a.lsum[k][c];
                if (v) atomicAdd(&gsum[((cur * Bn + b) * KCn + k) * CINn + c], v);
            }
            if (tid < KCn){
                unsigned v = sh.a.lcnt[tid];
                if (v) atomicAdd(&gcnt[(cur * Bn + b) * KCn + tid], v);
            }
        } else {
            if (tid < 128){
                int bi = sh.a.bi128[tid];
                idx [b * Sn + p] = bi;            // consumed by k_out (cross-kernel)
                idxf[b * Sn + p] = (float)bi;     // output
            }
            __syncthreads();
            // stable in-block ranks + publish per-(k,block) counts (pre-barrier)
            if (tid < KCn){
                int r = 0;
                for (int q = 0; q < 128; ++q)
                    if (sh.a.bi128[q] == tid) sh.a.rankF[q] = r++;
                AT_ST_U32(&blkcnt[(b * KCn + tid) * NBLK_B + tnum], (unsigned)r);
            }
        }
        batch_barrier(bar);
    }

    // ---------------- distributed stable sort: scan + scatter ----------------
    if (tid < KCn){
        unsigned run = 0, mybase = 0;
        #pragma unroll 4
        for (int t2 = 0; t2 < NBLK_B; ++t2){
            unsigned v = AT_LD_U32(&blkcnt[(b * KCn + tid) * NBLK_B + t2]);
            if (t2 == tnum) mybase = run;
            run += v;
        }
        sh.a.totK[tid]   = run;
        sh.a.baseBT[tid] = mybase;
    }
    __syncthreads();
    if (tid == 0){
        unsigned acc = 0;
        #pragma unroll
        for (int k = 0; k < KCn; ++k){ sh.a.goffK[k] = acc; acc += sh.a.totK[k]; }
        sh.a.goffK[KCn] = acc;
    }
    __syncthreads();
    if (tid < 128){
        int k = sh.a.bi128[tid];
        unsigned pos = sh.a.goffK[k] + sh.a.baseBT[k] + (unsigned)sh.a.rankF[tid];
        AT_ST_U32((unsigned*)&sorted[b * Sn + pos], (unsigned)(tnum * 128 + tid));
    }
    const int kk    = tnum;
    const int off0r = (int)sh.a.goffK[kk];
    const int nmy   = (int)sh.a.totK[kk];
    batch_barrier(bar);

    // ---------------- segmean (cluster kk), slot-parallel with ILP ----------
    // thread = (channel cA = tid>>3, pixel-slot s = tid&7); 9 taps in registers
    {
        const int cA = tid >> 3;
        const int s  = tid & 7;
        const float* xc = x + ((size_t)(b * CINn + cA) << 12);
        float acc[9];
        #pragma unroll
        for (int a = 0; a < 9; ++a) acc[a] = 0.f;

        for (int base = 0; base < nmy; base += 256){
            int m = min(256, nmy - base);
            __syncthreads();
            if (tid < m)
                sh.m.pl[tid] = (int)AT_LD_U32((unsigned*)&sorted[b * Sn + off0r + base + tid]);
            __syncthreads();
            #pragma unroll 2
            for (int i = s; i < m; i += 8){
                int pp = sh.m.pl[i];
                int py = pp >> 6, px2 = pp & 63;
                #pragma unroll
                for (int a = 0; a < 9; ++a){
                    int y1 = py + a / 3 - 1, x1 = px2 + (a % 3) - 1;
                    float v = (y1 >= 0 && y1 < Hn && x1 >= 0 && x1 < Wn)
                              ? xc[(y1 << 6) + x1] : 0.f;
                    acc[a] += v;
                }
            }
        }
        __syncthreads();
        #pragma unroll
        for (int a = 0; a < 9; ++a) sh.m.psum[cA][a][s] = acc[a];
        __syncthreads();
        // deterministic fixed-order 8-slot reduce -> centroid patch means
        float invn = 1.f / (float)max(nmy, 1);
        for (int f = tid; f < Fn; f += 256){
            int c = f / 9, a = f - c * 9;
            float sm = 0.f;
            #pragma unroll
            for (int s2 = 0; s2 < 8; ++s2) sm += sh.m.psum[c][a][s2];
            sh.m.centL[f] = sm * invn;
        }
    }
    __syncthreads();

    // ---------------- MLPs + heads ----------------
    {
        int j = tid & 15, rep = tid >> 4;
        float p1 = 0.f, p2 = 0.f;
        int fbeg = rep * 18;
        for (int ff = fbeg; ff < fbeg + 18; ++ff){
            float cv = sh.m.centL[ff];
            p1 = fmaf(cv, Wh1[ff * Mn + j], p1);
            p2 = fmaf(cv, Wb1[ff * Mn + j], p2);
        }
        sh.m.part1[rep][j] = p1;
        sh.m.part2[rep][j] = p2;
    }
    __syncthreads();
    if (tid < 32){
        int br = tid >> 4, j = tid & 15;
        float s = br ? bb1[j] : bh1[j];
        for (int r = 0; r < 16; ++r) s += br ? sh.m.part2[r][j] : sh.m.part1[r][j];
        sh.m.hL[br][j] = relu_(s);
    }
    __syncthreads();
    if (tid < 32){
        int br = tid >> 4, j = tid & 15;
        const float* W2 = br ? Wb2 : Wh2;
        float s = br ? bb2[j] : bh2[j];
        #pragma unroll
        for (int i = 0; i < Mn; ++i) s = fmaf(sh.m.hL[br][i], W2[i * Mn + j], s);
        sh.m.kfL[br][j] = relu_(s);
    }
    __syncthreads();
    if (tid < 32){
        int o = tid;
        float s1 = bc[o], s2 = bo[o], s3 = bb3[o];
        #pragma unroll
        for (int i = 0; i < Mn; ++i){
            float kv = sh.m.kfL[0][i];
            s1 = fmaf(kv, Wc[i * COUTn + o], s1);
            s2 = fmaf(kv, Wo[i * COUTn + o], s2);
            s3 = fmaf(sh.m.kfL[1][i], Wb3[i * COUTn + o], s3);
        }
        wcin [(b * KCn + kk) * CINn  + o] = sigmoid_(s1);
        wcout[(b * KCn + kk) * COUTn + o] = sigmoid_(s2);
        biasb[(b * KCn + kk) * COUTn + o] = s3;
    } else if (tid < 41){
        int a2 = tid - 32;
        float s = ba[a2];
        #pragma unroll
        for (int i = 0; i < Mn; ++i) s = fmaf(sh.m.kfL[0][i], Wa[i * AREAn + a2], s);
        warea[(b * KCn + kk) * AREAn + a2] = sigmoid_(s);
    }
}

// ---------------------------------------------------------------------------
// K2: grouped matmul over fixed 32-pixel tiles of the sorted array.
// ---------------------------------------------------------------------------
__global__ __launch_bounds__(256) void k_out(const float* __restrict__ x,
                                             const int* __restrict__ sorted,
                                             const int* __restrict__ idx,
                                             const float* __restrict__ wcin,
                                             const float* __restrict__ warea,
                                             const float* __restrict__ wcout,
                                             const float* __restrict__ biasb,
                                             const float* __restrict__ kern0,
                                             float* __restrict__ out){
    int b    = blockIdx.x >> 7;
    int tile = blockIdx.x & 127;
    int tid  = threadIdx.x;

    __shared__ float kernT[KCn * LDK];
    __shared__ float patchL[32 * LDK];
    __shared__ int   pix[32];
    __shared__ int   kid[32];
    __shared__ float wcl[CINn], wal[AREAn], wol[COUTn], biasL[COUTn];

    if (tid < 32){
        int pp = sorted[b * Sn + tile * 32 + tid];
        pix[tid] = pp;
        kid[tid] = idx[b * Sn + pp];
    }
    int fA = tid;       int cA = fA / 9, aA = fA - cA * 9;
    int dyA = aA / 3 - 1, dxA = aA % 3 - 1;
    int fB = 256 + tid; int cB = fB / 9, aB = fB - cB * 9;
    int dyB = aB / 3 - 1, dxB = aB % 3 - 1;
    __syncthreads();

    #pragma unroll 4
    for (int px = 0; px < 32; ++px){
        int pp = pix[px];
        int py = pp >> 6, pxx = pp & 63;
        int y1 = py + dyA, x1 = pxx + dxA;
        patchL[px * LDK + tid] = (y1 >= 0 && y1 < Hn && x1 >= 0 && x1 < Wn)
            ? x[((size_t)(b * CINn + cA) << 12) + (y1 << 6) + x1] : 0.f;
        if (tid < 32){
            int y2 = py + dyB, x2 = pxx + dxB;
            patchL[px * LDK + 256 + tid] = (y2 >= 0 && y2 < Hn && x2 >= 0 && x2 < Wn)
                ? x[((size_t)(b * CINn + cB) << 12) + (y2 << 6) + x2] : 0.f;
        }
    }

    int o2 = tid & 15, p2 = tid >> 4;
    int oA = o2 * 2, oB = o2 * 2 + 1;
    int pxA = p2 * 2, pxB = p2 * 2 + 1;

    int i0 = 0;
    while (i0 < 32){
        __syncthreads();
        int kcur = kid[i0];
        int i1 = i0 + 1;
        while (i1 < 32 && kid[i1] == kcur) ++i1;

        if (tid < 32)       wcl[tid]        = wcin [(b * KCn + kcur) * CINn  + tid];
        else if (tid < 64)  wol[tid - 32]   = wcout[(b * KCn + kcur) * COUTn + tid - 32];
        else if (tid < 73)  wal[tid - 64]   = warea[(b * KCn + kcur) * AREAn + tid - 64];
        else if (tid >= 96 && tid < 128) biasL[tid - 96] = biasb[(b * KCn + kcur) * COUTn + tid - 96];
        __syncthreads();

        {
            int o  = tid >> 3;
            int q  = tid & 7;
            int f0 = q * 36;
            int cc = q * 4, aa = 0;
            float wo_ = wol[o];
            float* kr = kernT + o * LDK + f0;
            #pragma unroll 4
            for (int i2 = 0; i2 < 36; ++i2){
                kr[i2] = wcl[cc] * wal[aa] * wo_ * kern0[(f0 + i2) * COUTn + o];
                if (++aa == 9){ aa = 0; ++cc; }
            }
        }
        __syncthreads();

        bool actA = (pxA >= i0 && pxA < i1);
        bool actB = (pxB >= i0 && pxB < i1);
        if (actA || actB){
            const float* krA = kernT + oA * LDK;
            const float* krB = kernT + oB * LDK;
            const float* prA = patchL + pxA * LDK;
            const float* prB = patchL + pxB * LDK;
            float s00 = 0.f, s01 = 0.f, s10 = 0.f, s11 = 0.f;
            if (actA && actB){
                #pragma unroll 4
                for (int fq = 0; fq < Fn; fq += 4){
                    float4 k0 = *reinterpret_cast<const float4*>(krA + fq);
                    float4 k1 = *reinterpret_cast<const float4*>(krB + fq);
                    float4 pa = *reinterpret_cast<const float4*>(prA + fq);
                    float4 pb = *reinterpret_cast<const float4*>(prB + fq);
                    s00 = fmaf(pa.x,k0.x,s00); s00 = fmaf(pa.y,k0.y,s00); s00 = fmaf(pa.z,k0.z,s00); s00 = fmaf(pa.w,k0.w,s00);
                    s01 = fmaf(pa.x,k1.x,s01); s01 = fmaf(pa.y,k1.y,s01); s01 = fmaf(pa.z,k1.z,s01); s01 = fmaf(pa.w,k1.w,s01);
                    s10 = fmaf(pb.x,k0.x,s10); s10 = fmaf(pb.y,k0.y,s10); s10 = fmaf(pb.z,k0.z,s10); s10 = fmaf(pb.w,k0.w,s10);
                    s11 = fmaf(pb.x,k1.x,s11); s11 = fmaf(pb.y,k1.y,s11); s11 = fmaf(pb.z,k1.z,s11); s11 = fmaf(pb.w,k1.w,s11);
                }
            } else {
                const float* pr = actA ? prA : prB;
                #pragma unroll 4
                for (int fq = 0; fq < Fn; fq += 4){
                    float4 k0 = *reinterpret_cast<const float4*>(krA + fq);
                    float4 k1 = *reinterpret_cast<const float4*>(krB + fq);
                    float4 pa = *reinterpret_cast<const float4*>(pr + fq);
                    s00 = fmaf(pa.x,k0.x,s00); s00 = fmaf(pa.y,k0.y,s00); s00 = fmaf(pa.z,k0.z,s00); s00 = fmaf(pa.w,k0.w,s00);
                    s01 = fmaf(pa.x,k1.x,s01); s01 = fmaf(pa.y,k1.y,s01); s01 = fmaf(pa.z,k1.z,s01); s01 = fmaf(pa.w,k1.w,s01);
                }
                if (actB){ s10 = s00; s11 = s01; s00 = 0.f; s01 = 0.f; }
            }
            if (actA){
                int pp = pix[pxA];
                out[((size_t)(b * COUTn + oA) << 12) + pp] = biasL[oA] + s00;
                out[((size_t)(b * COUTn + oB) << 12) + pp] = biasL[oB] + s01;
            }
            if (actB){
                int pp = pix[pxB];
                out[((size_t)(b * COUTn + oA) << 12) + pp] = biasL[oA] + s10;
                out[((size_t)(b * COUTn + oB) << 12) + pp] = biasL[oB] + s11;
            }
        }
        i0 = i1;
    }
}

// ---------------------------------------------------------------------------
extern "C" void kernel_launch(void* const* d_in, const int* in_sizes, int n_in,
                              void* d_out, int out_size, void* d_ws, size_t ws_size,
                              hipStream_t stream){
    const float* x    = (const float*)d_in[0];
    const float* Wh1  = (const float*)d_in[1];
    const float* bh1  = (const float*)d_in[2];
    const float* Wh2  = (const float*)d_in[3];
    const float* bh2  = (const float*)d_in[4];
    const float* Wa   = (const float*)d_in[5];
    const float* ba   = (const float*)d_in[6];
    const float* Wc   = (const float*)d_in[7];
    const float* bc   = (const float*)d_in[8];
    const float* Wo   = (const float*)d_in[9];
    const float* bo   = (const float*)d_in[10];
    const float* kern0= (const float*)d_in[11];
    const float* Wb1  = (const float*)d_in[12];
    const float* bb1  = (const float*)d_in[13];
    const float* Wb2  = (const float*)d_in[14];
    const float* bb2  = (const float*)d_in[15];
    const float* Wb3  = (const float*)d_in[16];
    const float* bb3  = (const float*)d_in[17];

    char* ws = (char*)d_ws;
    float*    feat   = (float*)(ws + 0);             // 2,097,152
    u64*      gsum   = (u64*)  (ws + 2097152);       //    98,304
    unsigned* gcnt   = (unsigned*)(ws + 2195456);    //     1,536
    unsigned* blkcnt = (unsigned*)(ws + 2196992);    //    16,384
    int*      idx    = (int*)  (ws + 2213376);       //    65,536
    int*      sorted = (int*)  (ws + 2278912);       //    65,536
    float*    wcin   = (float*)(ws + 2344448);       //    16,384
    float*    warea  = (float*)(ws + 2360832);       //     4,608
    float*    wcout  = (float*)(ws + 2365440);       //    16,384
    float*    biasb  = (float*)(ws + 2381824);       //    16,384
    unsigned* bars   = (unsigned*)(ws + 2398208);    //     1,024

    float* outp = (float*)d_out;
    float* idxf = outp + (size_t)Bn * COUTn * Sn;

    k_init<<<(Bn * CINn * Sn) / 256, 256, 0, stream>>>(x, feat, gsum, gcnt, bars);
    k_main<<<Bn * NBLK_B, 256, 0, stream>>>(x, feat, gsum, gcnt, blkcnt, idx, idxf,
                                            sorted,
                                            Wh1, bh1, Wh2, bh2, Wa, ba, Wc, bc, Wo, bo,
                                            Wb1, bb1, Wb2, bb2, Wb3, bb3,
                                            wcin, warea, wcout, biasb, bars);
    k_out<<<Bn * 128, 256, 0, stream>>>(x, sorted, idx, wcin, warea, wcout, biasb,
                                        kern0, outp);
}